// Round 1
// baseline (484.655 us; speedup 1.0000x reference)
//
#include <hip/hip_runtime.h>
#include <math.h>

// ---------------------------------------------------------------------------
// TransFrame: B=2, H=W=128, D=8, C=64 ; F_IN=F_OUT=512 ; HEADS=4, Dh=128
// Pipeline:
//   x_bf = bf16(x)                                 [32768 x 512]
//   Wcat_t = bf16([Wq|Wk|Wv]^T)                    [1536 x 512]
//   qkv = x_bf @ Wcat (MFMA, bf16 out)             [32768 x 1536]
//   ss[b][col] = sum_n q/k^2  (cols 0..1023)
//   G[b,h,d,e] = sum_n k[d,n] q[e,n]  (MFMA, atomics over 32 n-splits)
//   softmax(G * rsqrt(ssk)*rsqrt(ssq)*rescale) -> Abd block-diagonal bf16
//   Mt[b] = Wp_t @ Abd[b]   (MFMA)                 [512 x 512] (g-major)
//   out_c[b] = v @ Mt[b]^T + bp (MFMA, bf16 out)   [16384 x 512]
//   p1 = gelu(dwconv3(v, w1))  (bf16)
//   d_out = dwconv3(p1, w2) + out_c  (fp32)
// ---------------------------------------------------------------------------

using short8 = __attribute__((ext_vector_type(8))) short;
using f32x4  = __attribute__((ext_vector_type(4))) float;

__device__ __forceinline__ float bf2f(unsigned short u) {
  union { unsigned int i; float f; } v; v.i = ((unsigned int)u) << 16; return v.f;
}
__device__ __forceinline__ unsigned short f2bf(float f) {
  union { float f; unsigned int i; } v; v.f = f;
  unsigned int r = v.i + 0x7fffu + ((v.i >> 16) & 1u);
  return (unsigned short)(r >> 16);
}

// ---------------------------------------------------------------------------
// prep kernels
// ---------------------------------------------------------------------------
__global__ __launch_bounds__(256) void convert_x(const float* __restrict__ x,
                                                 unsigned short* __restrict__ xb) {
  int i = (blockIdx.x * 256 + threadIdx.x) * 4;
  float4 v = *(const float4*)&x[i];
  ushort4 o;
  o.x = f2bf(v.x); o.y = f2bf(v.y); o.z = f2bf(v.z); o.w = f2bf(v.w);
  *(ushort4*)&xb[i] = o;
}

// builds Wcat_t [1536x512] (rows = out col n, cols = k) and Wp_t [512x512]
__global__ __launch_bounds__(256) void prep_w(const float* __restrict__ Wq,
                                              const float* __restrict__ Wk,
                                              const float* __restrict__ Wv,
                                              const float* __restrict__ Wp,
                                              unsigned short* __restrict__ Wcat_t,
                                              unsigned short* __restrict__ Wp_t) {
  int i = blockIdx.x * 256 + threadIdx.x;
  if (i < 786432) {
    int nn = i >> 9, k = i & 511;
    const float* W = (nn < 512) ? Wq : ((nn < 1024) ? Wk : Wv);
    int n = nn & 511;
    Wcat_t[i] = f2bf(W[k * 512 + n]);
  } else {
    int j = i - 786432;
    int g = j >> 9, hd = j & 511;
    Wp_t[j] = f2bf(Wp[hd * 512 + g]);
  }
}

// ---------------------------------------------------------------------------
// Generic bf16 MFMA GEMM:  C[m][n] = sum_k A[m][k] * Bt[n][k]  (+ bias[n])
// Block tile 128x128, BK=32, 256 threads = 4 waves (2x2 of 64x64).
// LDS row stride 40 bf16 (=80B, 16B aligned, bank-spread).
// ---------------------------------------------------------------------------
__global__ __launch_bounds__(256) void gemm_bt(
    const unsigned short* __restrict__ A, const unsigned short* __restrict__ Bt,
    unsigned short* __restrict__ C, const float* __restrict__ bias,
    int lda, int ldb, int ldc, int K,
    long sA, long sB, long sC) {
  __shared__ unsigned short As[128 * 40];
  __shared__ unsigned short Bs[128 * 40];
  const int t = threadIdx.x;
  const int m0 = blockIdx.x * 128, n0 = blockIdx.y * 128;
  A += (long)blockIdx.z * sA; Bt += (long)blockIdx.z * sB; C += (long)blockIdx.z * sC;
  const int lane = t & 63, wave = t >> 6;
  const int wm = wave >> 1, wn = wave & 1;
  const int quad = lane >> 4, l16 = lane & 15;
  const int sRow = t >> 2, sCol = (t & 3) * 8;

  f32x4 acc[4][4] = {};

  for (int k0 = 0; k0 < K; k0 += 32) {
    *(uint4*)&As[sRow * 40 + sCol]        = *(const uint4*)&A[(long)(m0 + sRow) * lda + k0 + sCol];
    *(uint4*)&As[(sRow + 64) * 40 + sCol] = *(const uint4*)&A[(long)(m0 + sRow + 64) * lda + k0 + sCol];
    *(uint4*)&Bs[sRow * 40 + sCol]        = *(const uint4*)&Bt[(long)(n0 + sRow) * ldb + k0 + sCol];
    *(uint4*)&Bs[(sRow + 64) * 40 + sCol] = *(const uint4*)&Bt[(long)(n0 + sRow + 64) * ldb + k0 + sCol];
    __syncthreads();
    short8 af[4], bfr[4];
#pragma unroll
    for (int i = 0; i < 4; i++)
      af[i] = *(const short8*)&As[(wm * 64 + i * 16 + l16) * 40 + quad * 8];
#pragma unroll
    for (int j = 0; j < 4; j++)
      bfr[j] = *(const short8*)&Bs[(wn * 64 + j * 16 + l16) * 40 + quad * 8];
#pragma unroll
    for (int i = 0; i < 4; i++)
#pragma unroll
      for (int j = 0; j < 4; j++)
        acc[i][j] = __builtin_amdgcn_mfma_f32_16x16x32_bf16(af[i], bfr[j], acc[i][j], 0, 0, 0);
    __syncthreads();
  }

#pragma unroll
  for (int i = 0; i < 4; i++) {
    int row = m0 + wm * 64 + i * 16 + quad * 4;
#pragma unroll
    for (int j = 0; j < 4; j++) {
      int col = n0 + wn * 64 + j * 16 + l16;
      float bv = bias ? bias[col] : 0.0f;
#pragma unroll
      for (int r = 0; r < 4; r++) {
        float v = acc[i][j][r] + bv;
        C[(long)(row + r) * ldc + col] = f2bf(v);
      }
    }
  }
}

// ---------------------------------------------------------------------------
// sumsq over n for q,k columns:  ss[b][col] += sum val^2, col in [0,1024)
// grid (cg=16, nchunk=8, b=2), 256 threads
// ---------------------------------------------------------------------------
__global__ __launch_bounds__(256) void sumsq_kernel(const unsigned short* __restrict__ qkv,
                                                    float* __restrict__ ss) {
  int cg = blockIdx.x, nc = blockIdx.y, b = blockIdx.z;
  int t = threadIdx.x;
  int col = cg * 64 + (t & 63);
  int noff = t >> 6;
  long base = (long)(b * 16384 + nc * 2048) * 1536;
  float a = 0.0f;
  for (int i = 0; i < 512; i++) {
    int n = i * 4 + noff;
    float v = bf2f(qkv[base + (long)n * 1536 + col]);
    a += v * v;
  }
  __shared__ float sm[256];
  sm[t] = a;
  __syncthreads();
  if (t < 64) {
    float s = sm[t] + sm[t + 64] + sm[t + 128] + sm[t + 192];
    atomicAdd(&ss[b * 1024 + cg * 64 + t], s);
  }
}

// ---------------------------------------------------------------------------
// Gram: G[b,h,d,e] += sum_{n in split} k[d,n]*q[e,n]   (MFMA over 128x128)
// grid (ns=32, h=4, b=2); per block 512 n in 16 stages of 32.
// LDS transposed staging: Ks/Qs [128 cols][32 n] stride 40.
// ---------------------------------------------------------------------------
__global__ __launch_bounds__(256) void gram_kernel(const unsigned short* __restrict__ qkv,
                                                   float* __restrict__ G) {
  __shared__ unsigned short Ks[128 * 40];
  __shared__ unsigned short Qs[128 * 40];
  int ns = blockIdx.x, h = blockIdx.y, b = blockIdx.z;
  int t = threadIdx.x;
  const int lane = t & 63, wave = t >> 6;
  const int wm = wave >> 1, wn = wave & 1;
  const int quad = lane >> 4, l16 = lane & 15;
  long base = (long)b * 16384 * 1536;
  int qcol = h * 128, kcol = 512 + h * 128;

  f32x4 acc[4][4] = {};

  for (int s = 0; s < 16; s++) {
    int n0 = ns * 512 + s * 32;
#pragma unroll
    for (int L = 0; L < 2; L++) {
      int lid = L * 256 + t;
      int r = lid >> 4, cg = lid & 15;
      uint4 q8 = *(const uint4*)&qkv[base + (long)(n0 + r) * 1536 + qcol + cg * 8];
      uint4 k8 = *(const uint4*)&qkv[base + (long)(n0 + r) * 1536 + kcol + cg * 8];
      const unsigned short* qp = (const unsigned short*)&q8;
      const unsigned short* kp = (const unsigned short*)&k8;
#pragma unroll
      for (int j = 0; j < 8; j++) {
        Qs[(cg * 8 + j) * 40 + r] = qp[j];
        Ks[(cg * 8 + j) * 40 + r] = kp[j];
      }
    }
    __syncthreads();
    short8 af[4], bfr[4];
#pragma unroll
    for (int i = 0; i < 4; i++)
      af[i] = *(const short8*)&Ks[(wm * 64 + i * 16 + l16) * 40 + quad * 8];
#pragma unroll
    for (int j = 0; j < 4; j++)
      bfr[j] = *(const short8*)&Qs[(wn * 64 + j * 16 + l16) * 40 + quad * 8];
#pragma unroll
    for (int i = 0; i < 4; i++)
#pragma unroll
      for (int j = 0; j < 4; j++)
        acc[i][j] = __builtin_amdgcn_mfma_f32_16x16x32_bf16(af[i], bfr[j], acc[i][j], 0, 0, 0);
    __syncthreads();
  }

  float* g = G + (long)(b * 4 + h) * 16384;
#pragma unroll
  for (int i = 0; i < 4; i++) {
    int row = wm * 64 + i * 16 + quad * 4;
#pragma unroll
    for (int j = 0; j < 4; j++) {
      int col = wn * 64 + j * 16 + l16;
#pragma unroll
      for (int r = 0; r < 4; r++)
        atomicAdd(&g[(row + r) * 128 + col], acc[i][j][r]);
    }
  }
}

// ---------------------------------------------------------------------------
// softmax over e (per row d) of scaled G; writes attn into block-diagonal Abd
// Abd[b][(h*128+e)][(h*128+d)] = attn[h][d][e]   (bf16; rest pre-zeroed)
// grid (h=4, b=2), 256 threads
// ---------------------------------------------------------------------------
__global__ __launch_bounds__(256) void softmax_kernel(const float* __restrict__ G,
                                                      const float* __restrict__ ss,
                                                      const float* __restrict__ rescale,
                                                      unsigned short* __restrict__ Abd) {
  __shared__ float L[128 * 129];
  __shared__ float rsq[128];
  __shared__ float rsk[128];
  int h = blockIdx.x, b = blockIdx.y;
  int t = threadIdx.x;
  const float* g = G + (long)(b * 4 + h) * 16384;
  if (t < 128) rsq[t] = rsqrtf(fmaxf(ss[b * 1024 + h * 128 + t], 1e-24f));
  else if (t < 256) { int d = t - 128; rsk[d] = rsqrtf(fmaxf(ss[b * 1024 + 512 + h * 128 + d], 1e-24f)); }
  __syncthreads();
  float rs = rescale[h];
  for (int i = t; i < 16384; i += 256) {
    int d = i >> 7, e = i & 127;
    L[d * 129 + e] = g[i] * rsk[d] * rsq[e] * rs;
  }
  __syncthreads();
  if (t < 128) {
    float* row = &L[t * 129];
    float mx = -1e30f;
    for (int e = 0; e < 128; e++) mx = fmaxf(mx, row[e]);
    float sum = 0.0f;
    for (int e = 0; e < 128; e++) { float ex = __expf(row[e] - mx); row[e] = ex; sum += ex; }
    float inv = 1.0f / sum;
    long abase = (long)b * 262144;
    for (int e = 0; e < 128; e++)
      Abd[abase + (long)(h * 128 + e) * 512 + h * 128 + t] = f2bf(row[e] * inv);
  }
}

// ---------------------------------------------------------------------------
// depthwise 3x3x3 conv over (d,h,w), channels c; feature f = d*64+c.
// GELU variant writes bf16; ADD variant adds out_c and writes fp32.
// grid (wt=16, ht=16, b=2), 256 threads; LDS tile 10x10 hw x 512 f.
// ---------------------------------------------------------------------------
template <bool GELU, bool ADD>
__global__ __launch_bounds__(256) void dwconv_kernel(
    const unsigned short* __restrict__ in, int inld,
    const float* __restrict__ wgt,
    const unsigned short* __restrict__ addc,
    unsigned short* __restrict__ outb,
    float* __restrict__ outf) {
  __shared__ unsigned short tile[100 * 512];
  __shared__ float wl[27 * 64];
  int wt = blockIdx.x, ht = blockIdx.y, b = blockIdx.z;
  int t = threadIdx.x;
  for (int i = t; i < 1728; i += 256) {
    int c = i / 27, tap = i % 27;
    wl[tap * 64 + c] = wgt[i];
  }
  int h0 = ht * 8, w0 = wt * 8;
  int lg = t & 63;
#pragma unroll 5
  for (int rr = 0; rr < 25; rr++) {
    int row = rr * 4 + (t >> 6);
    int hh = row / 10, ww = row % 10;
    int gh = h0 + hh - 1, gw = w0 + ww - 1;
    uint4 v = {0u, 0u, 0u, 0u};
    if ((unsigned)gh < 128u && (unsigned)gw < 128u)
      v = *(const uint4*)&in[(long)(b * 16384 + gh * 128 + gw) * inld + lg * 8];
    *(uint4*)&tile[row * 512 + lg * 8] = v;
  }
  __syncthreads();

  int f0 = lg * 8;
  int d = f0 >> 6, c0 = f0 & 63;
  int pg = t >> 6;
  for (int P = 0; P < 4; P++) {
    float acc[4][8] = {};
    for (int kd = 0; kd < 3; kd++) {
      int dz = d + kd - 1;
      if ((unsigned)dz >= 8u) continue;
      int fz = dz * 64 + c0;
#pragma unroll
      for (int kh = 0; kh < 3; kh++)
#pragma unroll
        for (int kw = 0; kw < 3; kw++) {
          int tap = kd * 9 + kh * 3 + kw;
          float w[8];
          *(float4*)&w[0] = *(const float4*)&wl[tap * 64 + c0];
          *(float4*)&w[4] = *(const float4*)&wl[tap * 64 + c0 + 4];
#pragma unroll
          for (int s = 0; s < 4; s++) {
            int pos = P * 16 + pg * 4 + s;
            int ph = pos >> 3, pw = pos & 7;
            uint4 pv = *(const uint4*)&tile[((ph + kh) * 10 + pw + kw) * 512 + fz];
            const unsigned short* u = (const unsigned short*)&pv;
#pragma unroll
            for (int j = 0; j < 8; j++) acc[s][j] += bf2f(u[j]) * w[j];
          }
        }
    }
    for (int s = 0; s < 4; s++) {
      int pos = P * 16 + pg * 4 + s;
      int ph = pos >> 3, pw = pos & 7;
      long row = (long)(b * 16384 + (h0 + ph) * 128 + (w0 + pw));
      if (GELU) {
        unsigned short o[8];
#pragma unroll
        for (int j = 0; j < 8; j++) {
          float x = acc[s][j];
          o[j] = f2bf(0.5f * x * (1.0f + erff(x * 0.70710678118654752f)));
        }
        *(uint4*)&outb[row * 512 + f0] = *(uint4*)&o[0];
      } else {
        uint4 av = *(const uint4*)&addc[row * 512 + f0];
        const unsigned short* au = (const unsigned short*)&av;
        float o[8];
#pragma unroll
        for (int j = 0; j < 8; j++) o[j] = acc[s][j] + bf2f(au[j]);
        *(float4*)&outf[row * 512 + f0]     = *(float4*)&o[0];
        *(float4*)&outf[row * 512 + f0 + 4] = *(float4*)&o[4];
      }
    }
  }
}

// ---------------------------------------------------------------------------
// launch
// ---------------------------------------------------------------------------
extern "C" void kernel_launch(void* const* d_in, const int* in_sizes, int n_in,
                              void* d_out, int out_size, void* d_ws, size_t ws_size,
                              hipStream_t stream) {
  const float* x   = (const float*)d_in[0];
  const float* Wq  = (const float*)d_in[1];
  const float* Wk  = (const float*)d_in[2];
  const float* Wv  = (const float*)d_in[3];
  const float* rsc = (const float*)d_in[4];
  const float* Wp  = (const float*)d_in[5];
  const float* bp  = (const float*)d_in[6];
  const float* pw1 = (const float*)d_in[7];
  const float* pw2 = (const float*)d_in[8];
  float* out = (float*)d_out;

  char* ws = (char*)d_ws;
  // workspace layout (bytes); p1 reuses x_bf (dead after QKV GEMM)
  unsigned short* x_bf   = (unsigned short*)(ws + 0);           // 33,554,432
  unsigned short* qkv    = (unsigned short*)(ws + 33554432);    // 100,663,296
  unsigned short* Wcat_t = (unsigned short*)(ws + 134217728);   // 1,572,864
  unsigned short* Wp_t   = (unsigned short*)(ws + 135790592);   // 524,288
  float*          ss     = (float*)(ws + 136314880);            // 8,192
  float*          G      = (float*)(ws + 136323072);            // 524,288
  unsigned short* Abd    = (unsigned short*)(ws + 136847360);   // 1,048,576
  unsigned short* Mt     = (unsigned short*)(ws + 137895936);   // 1,048,576
  unsigned short* out_c  = (unsigned short*)(ws + 138944512);   // 33,554,432
  unsigned short* p1     = x_bf;                                 // reuse

  hipMemsetAsync(ss, 0, 8192, stream);
  hipMemsetAsync(G, 0, 524288, stream);
  hipMemsetAsync(Abd, 0, 1048576, stream);

  convert_x<<<16384, 256, 0, stream>>>(x, x_bf);
  prep_w<<<4096, 256, 0, stream>>>(Wq, Wk, Wv, Wp, Wcat_t, Wp_t);

  // qkv = x_bf @ Wcat : M=32768 N=1536 K=512
  gemm_bt<<<dim3(256, 12, 1), 256, 0, stream>>>(
      x_bf, Wcat_t, qkv, nullptr, 512, 512, 1536, 512, 0L, 0L, 0L);

  sumsq_kernel<<<dim3(16, 8, 2), 256, 0, stream>>>(qkv, ss);
  gram_kernel<<<dim3(32, 4, 2), 256, 0, stream>>>(qkv, G);
  softmax_kernel<<<dim3(4, 2, 1), 256, 0, stream>>>(G, ss, rsc, Abd);

  // Mt[b] = Wp_t @ Abd[b]^T : M=512 N=512 K=512, batch 2
  gemm_bt<<<dim3(4, 4, 2), 256, 0, stream>>>(
      Wp_t, Abd, Mt, nullptr, 512, 512, 512, 512, 0L, 262144L, 262144L);

  // out_c[b] = v @ Mt[b]^T + bp : M=16384 N=512 K=512, batch 2
  gemm_bt<<<dim3(128, 4, 2), 256, 0, stream>>>(
      qkv + 1024, Mt, out_c, bp, 1536, 512, 512, 512,
      (long)16384 * 1536, 262144L, (long)16384 * 512);

  // positional branch
  dwconv_kernel<true, false><<<dim3(16, 16, 2), 256, 0, stream>>>(
      qkv + 1024, 1536, pw1, nullptr, p1, nullptr);
  dwconv_kernel<false, true><<<dim3(16, 16, 2), 256, 0, stream>>>(
      p1, 512, pw2, out_c, nullptr, out);
}

// Round 2
// 416.948 us; speedup vs baseline: 1.1624x; 1.1624x over previous
//
#include <hip/hip_runtime.h>
#include <math.h>
#include <stdint.h>

// ---------------------------------------------------------------------------
// TransFrame: B=2, H=W=128, D=8, C=64 ; F_IN=F_OUT=512 ; HEADS=4, Dh=128
//   x_bf = bf16(x)                                  [32768 x 512]
//   Wcat_t = bf16([Wq|Wk|Wv]^T), Wp_t = bf16(Wp^T)  (LDS-tiled transpose)
//   qkv = x_bf @ Wcat (MFMA, global_load_lds)  + fused sumsq(q,k) -> ss
//   G[b,h,d,e] = sum_n k[d,n] q[e,n]  (MFMA, 64 n-splits, atomics)
//   softmax(G * rsqrt(ssk)*rsqrt(ssq)*rescale) -> Abd block-diagonal bf16
//   Mt[b] = Wp_t @ Abd[b]                           [512 x 512]
//   out_c[b] = v @ Mt[b]^T + bp                     [16384 x 512]
//   p1 = gelu(dwconv3(v, w1));  d_out = dwconv3(p1, w2) + out_c
// ---------------------------------------------------------------------------

using short8  = __attribute__((ext_vector_type(8))) short;
using short4v = __attribute__((ext_vector_type(4))) short;
using f32x4   = __attribute__((ext_vector_type(4))) float;

__device__ __forceinline__ float bf2f(unsigned short u) {
  union { unsigned int i; float f; } v; v.i = ((unsigned int)u) << 16; return v.f;
}
__device__ __forceinline__ unsigned short f2bf(float f) {
  union { float f; unsigned int i; } v; v.f = f;
  unsigned int r = v.i + 0x7fffu + ((v.i >> 16) & 1u);
  return (unsigned short)(r >> 16);
}

// async global->LDS, 16B per lane. LDS dst is wave-uniform base + lane*16.
__device__ __forceinline__ void g2l16(const void* g, void* l) {
  __builtin_amdgcn_global_load_lds(
      (__attribute__((address_space(1))) void*)(unsigned long long)(uintptr_t)g,
      (__attribute__((address_space(3))) void*)(unsigned int)(uintptr_t)l,
      16, 0, 0);
}

// ---------------------------------------------------------------------------
__global__ __launch_bounds__(256) void convert_x(const float* __restrict__ x,
                                                 unsigned short* __restrict__ xb) {
  int i = (blockIdx.x * 256 + threadIdx.x) * 4;
  float4 v = *(const float4*)&x[i];
  ushort4 o;
  o.x = f2bf(v.x); o.y = f2bf(v.y); o.z = f2bf(v.z); o.w = f2bf(v.w);
  *(ushort4*)&xb[i] = o;
}

// LDS-tiled transpose of the 4 weight matrices (coalesced both sides).
// grid 1024: mat = bid>>8 (0..2 -> Wcat_t rows mat*512.., 3 -> Wp_t)
__global__ __launch_bounds__(256) void prep_w(const float* __restrict__ Wq,
                                              const float* __restrict__ Wk,
                                              const float* __restrict__ Wv,
                                              const float* __restrict__ Wp,
                                              unsigned short* __restrict__ Wcat_t,
                                              unsigned short* __restrict__ Wp_t) {
  __shared__ unsigned short Ls[32 * 36];
  int bid = blockIdx.x;
  int mat = bid >> 8, tile = bid & 255;
  int tr = (tile >> 4) * 32, tc = (tile & 15) * 32;
  const float* src = (mat == 0) ? Wq : (mat == 1) ? Wk : (mat == 2) ? Wv : Wp;
  int t = threadIdx.x;
  int r = t >> 3, c4 = (t & 7) * 4;
  float4 v = *(const float4*)&src[(tr + r) * 512 + tc + c4];
  Ls[(c4 + 0) * 36 + r] = f2bf(v.x);
  Ls[(c4 + 1) * 36 + r] = f2bf(v.y);
  Ls[(c4 + 2) * 36 + r] = f2bf(v.z);
  Ls[(c4 + 3) * 36 + r] = f2bf(v.w);
  __syncthreads();
  int rn = t >> 3, ck4 = (t & 7) * 4;
  ushort4 o;
  o.x = Ls[rn * 36 + ck4 + 0]; o.y = Ls[rn * 36 + ck4 + 1];
  o.z = Ls[rn * 36 + ck4 + 2]; o.w = Ls[rn * 36 + ck4 + 3];
  unsigned short* dst = (mat < 3)
      ? &Wcat_t[(long)(mat * 512 + tc + rn) * 512 + tr + ck4]
      : &Wp_t[(long)(tc + rn) * 512 + tr + ck4];
  *(ushort4*)dst = o;
}

// ---------------------------------------------------------------------------
// bf16 MFMA GEMM with global_load_lds staging, XOR-swizzled BK=64 LDS.
// C[m][n] = sum_k A[m][k]*Bt[n][k] (+bias). If ss && n0<1024: fused column
// sum-of-squares (fp32, pre-rounding) atomically added to ss[b*1024+col].
// Tile 128x128, 256 threads (2x2 waves of 64x64).
// ---------------------------------------------------------------------------
__global__ __launch_bounds__(256) void gemm_lds(
    const unsigned short* __restrict__ A, const unsigned short* __restrict__ Bt,
    unsigned short* __restrict__ C, const float* __restrict__ bias,
    float* __restrict__ ss,
    int lda, int ldb, int ldc, int K, long sA, long sB, long sC) {
  __shared__ unsigned short As[128 * 64];
  __shared__ unsigned short Bs[128 * 64];
  const int t = threadIdx.x;
  const int m0 = blockIdx.x * 128, n0 = blockIdx.y * 128;
  A  += (long)blockIdx.z * sA + (long)m0 * lda;
  Bt += (long)blockIdx.z * sB + (long)n0 * ldb;
  C  += (long)blockIdx.z * sC;
  const int lane = t & 63, w = t >> 6;
  const int wm = w >> 1, wn = w & 1;
  const int quad = lane >> 4, l16 = lane & 15;
  const int sr = lane >> 3;   // row within 8-row staging group
  const int sc = lane & 7;    // 16B slot within 128B row

  f32x4 acc[4][4] = {};

  for (int k0 = 0; k0 < K; k0 += 64) {
#pragma unroll
    for (int q = 0; q < 4; q++) {
      int r = q * 32 + w * 8 + sr;
      int ca = (sc ^ sr) * 8;              // chunk for this lane's slot
      g2l16(&A[(long)r * lda + k0 + ca], &As[(q * 32 + w * 8) * 64]);
      g2l16(&Bt[(long)r * ldb + k0 + ca], &Bs[(q * 32 + w * 8) * 64]);
    }
    __syncthreads();
#pragma unroll
    for (int kk = 0; kk < 2; kk++) {
      short8 af[4], bfq[4];
#pragma unroll
      for (int i = 0; i < 4; i++) {
        int r = wm * 64 + i * 16 + l16;
        int s = (kk * 4 + quad) ^ (r & 7);
        af[i] = *(const short8*)&As[r * 64 + s * 8];
      }
#pragma unroll
      for (int j = 0; j < 4; j++) {
        int r = wn * 64 + j * 16 + l16;
        int s = (kk * 4 + quad) ^ (r & 7);
        bfq[j] = *(const short8*)&Bs[r * 64 + s * 8];
      }
#pragma unroll
      for (int i = 0; i < 4; i++)
#pragma unroll
        for (int j = 0; j < 4; j++)
          acc[i][j] = __builtin_amdgcn_mfma_f32_16x16x32_bf16(af[i], bfq[j], acc[i][j], 0, 0, 0);
    }
    __syncthreads();
  }

#pragma unroll
  for (int i = 0; i < 4; i++) {
    int row = m0 + wm * 64 + i * 16 + quad * 4;
#pragma unroll
    for (int j = 0; j < 4; j++) {
      int col = n0 + wn * 64 + j * 16 + l16;
      float bv = bias ? bias[col] : 0.0f;
#pragma unroll
      for (int r = 0; r < 4; r++)
        C[(long)(row + r) * ldc + col] = f2bf(acc[i][j][r] + bv);
    }
  }

  if (ss != nullptr && n0 < 1024) {
    float part[4];
#pragma unroll
    for (int j = 0; j < 4; j++) {
      float p = 0.0f;
#pragma unroll
      for (int i = 0; i < 4; i++)
#pragma unroll
        for (int r = 0; r < 4; r++) p += acc[i][j][r] * acc[i][j][r];
      part[j] = p;
    }
    float* red = (float*)As;   // 8 x 128 floats, As dead after main loop
    int g = wm * 4 + quad;
#pragma unroll
    for (int j = 0; j < 4; j++) red[g * 128 + wn * 64 + j * 16 + l16] = part[j];
    __syncthreads();
    if (t < 128) {
      float s = 0.0f;
#pragma unroll
      for (int g2 = 0; g2 < 8; g2++) s += red[g2 * 128 + t];
      int b = m0 >> 14;
      atomicAdd(&ss[b * 1024 + n0 + t], s);
    }
  }
}

// ---------------------------------------------------------------------------
// Gram: G[b,h,d,e] += sum_{n in split} k[d,n]*q[e,n]; 64 splits of 256 n.
// Register-transpose staging: uint2 loads (4 cols x 8 n) -> ushort4 LDS
// writes; col-major LDS [col][32n] stride 36; b64-pair fragment reads (free).
// ---------------------------------------------------------------------------
__global__ __launch_bounds__(256) void gram_kernel(const unsigned short* __restrict__ qkv,
                                                   float* __restrict__ G) {
  __shared__ unsigned short Qs[128 * 36];
  __shared__ unsigned short Ks[128 * 36];
  int ns = blockIdx.x, h = blockIdx.y, b = blockIdx.z;
  int t = threadIdx.x;
  const int lane = t & 63, wave = t >> 6;
  const int wm = wave >> 1, wn = wave & 1;
  const int quad = lane >> 4, l16 = lane & 15;
  long base = (long)b * 16384 * 1536;
  // staging role
  int m = t >> 7;          // 0 = Q, 1 = K
  int tt = t & 127;
  int cg = tt & 31;        // col group of 4
  int rg = tt >> 5;        // n group of 8
  int colb = (m ? (512 + h * 128) : (h * 128)) + cg * 4;
  unsigned short* dst = m ? Ks : Qs;

  f32x4 acc[4][4] = {};

  for (int s = 0; s < 8; s++) {
    int n0 = ns * 256 + s * 32;
    unsigned short sv[8][4];
#pragma unroll
    for (int rr = 0; rr < 8; rr++) {
      int n = n0 + rg * 8 + rr;
      uint2 v = *(const uint2*)&qkv[base + (long)n * 1536 + colb];
      sv[rr][0] = (unsigned short)(v.x & 0xffff);
      sv[rr][1] = (unsigned short)(v.x >> 16);
      sv[rr][2] = (unsigned short)(v.y & 0xffff);
      sv[rr][3] = (unsigned short)(v.y >> 16);
    }
#pragma unroll
    for (int j = 0; j < 4; j++) {
      int col = cg * 4 + j;
      ushort4 w0 = { sv[0][j], sv[1][j], sv[2][j], sv[3][j] };
      ushort4 w1 = { sv[4][j], sv[5][j], sv[6][j], sv[7][j] };
      *(ushort4*)&dst[col * 36 + rg * 8]     = w0;
      *(ushort4*)&dst[col * 36 + rg * 8 + 4] = w1;
    }
    __syncthreads();
    short8 af[4], bfq[4];
#pragma unroll
    for (int i = 0; i < 4; i++) {
      const unsigned short* p = &Ks[(wm * 64 + i * 16 + l16) * 36 + quad * 8];
      union { short8 v8; short4v v4[2]; } u;
      u.v4[0] = *(const short4v*)p; u.v4[1] = *(const short4v*)(p + 4);
      af[i] = u.v8;
    }
#pragma unroll
    for (int j = 0; j < 4; j++) {
      const unsigned short* p = &Qs[(wn * 64 + j * 16 + l16) * 36 + quad * 8];
      union { short8 v8; short4v v4[2]; } u;
      u.v4[0] = *(const short4v*)p; u.v4[1] = *(const short4v*)(p + 4);
      bfq[j] = u.v8;
    }
#pragma unroll
    for (int i = 0; i < 4; i++)
#pragma unroll
      for (int j = 0; j < 4; j++)
        acc[i][j] = __builtin_amdgcn_mfma_f32_16x16x32_bf16(af[i], bfq[j], acc[i][j], 0, 0, 0);
    __syncthreads();
  }

  float* g = G + (long)(b * 4 + h) * 16384;
#pragma unroll
  for (int i = 0; i < 4; i++) {
    int row = wm * 64 + i * 16 + quad * 4;
#pragma unroll
    for (int j = 0; j < 4; j++) {
      int col = wn * 64 + j * 16 + l16;
#pragma unroll
      for (int r = 0; r < 4; r++)
        atomicAdd(&g[(row + r) * 128 + col], acc[i][j][r]);
    }
  }
}

// ---------------------------------------------------------------------------
// softmax over e of scaled G; writes block-diagonal Abd (bf16, rest zeroed).
// ---------------------------------------------------------------------------
__global__ __launch_bounds__(256) void softmax_kernel(const float* __restrict__ G,
                                                      const float* __restrict__ ss,
                                                      const float* __restrict__ rescale,
                                                      unsigned short* __restrict__ Abd) {
  __shared__ float L[128 * 129];
  __shared__ float rsq[128];
  __shared__ float rsk[128];
  int h = blockIdx.x, b = blockIdx.y;
  int t = threadIdx.x;
  const float* g = G + (long)(b * 4 + h) * 16384;
  if (t < 128) rsq[t] = rsqrtf(fmaxf(ss[b * 1024 + h * 128 + t], 1e-24f));
  else if (t < 256) { int d = t - 128; rsk[d] = rsqrtf(fmaxf(ss[b * 1024 + 512 + h * 128 + d], 1e-24f)); }
  __syncthreads();
  float rs = rescale[h];
  for (int i = t; i < 16384; i += 256) {
    int d = i >> 7, e = i & 127;
    L[d * 129 + e] = g[i] * rsk[d] * rsq[e] * rs;
  }
  __syncthreads();
  if (t < 128) {
    float* row = &L[t * 129];
    float mx = -1e30f;
    for (int e = 0; e < 128; e++) mx = fmaxf(mx, row[e]);
    float sum = 0.0f;
    for (int e = 0; e < 128; e++) { float ex = __expf(row[e] - mx); row[e] = ex; sum += ex; }
    float inv = 1.0f / sum;
    long abase = (long)b * 262144;
    for (int e = 0; e < 128; e++)
      Abd[abase + (long)(h * 128 + e) * 512 + h * 128 + t] = f2bf(row[e] * inv);
  }
}

// ---------------------------------------------------------------------------
// depthwise 3x3x3 conv over (d,h,w); feature f = d*64+c.
// ---------------------------------------------------------------------------
template <bool GELU, bool ADD>
__global__ __launch_bounds__(256) void dwconv_kernel(
    const unsigned short* __restrict__ in, int inld,
    const float* __restrict__ wgt,
    const unsigned short* __restrict__ addc,
    unsigned short* __restrict__ outb,
    float* __restrict__ outf) {
  __shared__ unsigned short tile[100 * 512];
  __shared__ float wl[27 * 64];
  int wt = blockIdx.x, ht = blockIdx.y, b = blockIdx.z;
  int t = threadIdx.x;
  for (int i = t; i < 1728; i += 256) {
    int c = i / 27, tap = i % 27;
    wl[tap * 64 + c] = wgt[i];
  }
  int h0 = ht * 8, w0 = wt * 8;
  int lg = t & 63;
#pragma unroll 5
  for (int rr = 0; rr < 25; rr++) {
    int row = rr * 4 + (t >> 6);
    int hh = row / 10, ww = row % 10;
    int gh = h0 + hh - 1, gw = w0 + ww - 1;
    uint4 v = {0u, 0u, 0u, 0u};
    if ((unsigned)gh < 128u && (unsigned)gw < 128u)
      v = *(const uint4*)&in[(long)(b * 16384 + gh * 128 + gw) * inld + lg * 8];
    *(uint4*)&tile[row * 512 + lg * 8] = v;
  }
  __syncthreads();

  int f0 = lg * 8;
  int d = f0 >> 6, c0 = f0 & 63;
  int pg = t >> 6;
  for (int P = 0; P < 4; P++) {
    float acc[4][8] = {};
    for (int kd = 0; kd < 3; kd++) {
      int dz = d + kd - 1;
      if ((unsigned)dz >= 8u) continue;
      int fz = dz * 64 + c0;
#pragma unroll
      for (int kh = 0; kh < 3; kh++)
#pragma unroll
        for (int kw = 0; kw < 3; kw++) {
          int tap = kd * 9 + kh * 3 + kw;
          float w[8];
          *(float4*)&w[0] = *(const float4*)&wl[tap * 64 + c0];
          *(float4*)&w[4] = *(const float4*)&wl[tap * 64 + c0 + 4];
#pragma unroll
          for (int s = 0; s < 4; s++) {
            int pos = P * 16 + pg * 4 + s;
            int ph = pos >> 3, pw = pos & 7;
            uint4 pv = *(const uint4*)&tile[((ph + kh) * 10 + pw + kw) * 512 + fz];
            const unsigned short* u = (const unsigned short*)&pv;
#pragma unroll
            for (int j = 0; j < 8; j++) acc[s][j] += bf2f(u[j]) * w[j];
          }
        }
    }
    for (int s = 0; s < 4; s++) {
      int pos = P * 16 + pg * 4 + s;
      int ph = pos >> 3, pw = pos & 7;
      long row = (long)(b * 16384 + (h0 + ph) * 128 + (w0 + pw));
      if (GELU) {
        unsigned short o[8];
#pragma unroll
        for (int j = 0; j < 8; j++) {
          float x = acc[s][j];
          o[j] = f2bf(0.5f * x * (1.0f + erff(x * 0.70710678118654752f)));
        }
        *(uint4*)&outb[row * 512 + f0] = *(uint4*)&o[0];
      } else {
        uint4 av = *(const uint4*)&addc[row * 512 + f0];
        const unsigned short* au = (const unsigned short*)&av;
        float o[8];
#pragma unroll
        for (int j = 0; j < 8; j++) o[j] = acc[s][j] + bf2f(au[j]);
        *(float4*)&outf[row * 512 + f0]     = *(float4*)&o[0];
        *(float4*)&outf[row * 512 + f0 + 4] = *(float4*)&o[4];
      }
    }
  }
}

// ---------------------------------------------------------------------------
extern "C" void kernel_launch(void* const* d_in, const int* in_sizes, int n_in,
                              void* d_out, int out_size, void* d_ws, size_t ws_size,
                              hipStream_t stream) {
  const float* x   = (const float*)d_in[0];
  const float* Wq  = (const float*)d_in[1];
  const float* Wk  = (const float*)d_in[2];
  const float* Wv  = (const float*)d_in[3];
  const float* rsc = (const float*)d_in[4];
  const float* Wp  = (const float*)d_in[5];
  const float* bp  = (const float*)d_in[6];
  const float* pw1 = (const float*)d_in[7];
  const float* pw2 = (const float*)d_in[8];
  float* out = (float*)d_out;

  char* ws = (char*)d_ws;
  unsigned short* x_bf   = (unsigned short*)(ws + 0);           // 33,554,432
  unsigned short* qkv    = (unsigned short*)(ws + 33554432);    // 100,663,296
  unsigned short* Wcat_t = (unsigned short*)(ws + 134217728);   // 1,572,864
  unsigned short* Wp_t   = (unsigned short*)(ws + 135790592);   // 524,288
  float*          ss     = (float*)(ws + 136314880);            // 8,192
  float*          G      = (float*)(ws + 136323072);            // 524,288
  unsigned short* Abd    = (unsigned short*)(ws + 136847360);   // 1,048,576
  unsigned short* Mt     = (unsigned short*)(ws + 137895936);   // 1,048,576
  unsigned short* out_c  = (unsigned short*)(ws + 138944512);   // 33,554,432
  unsigned short* p1     = x_bf;                                 // reuse

  hipMemsetAsync(ss, 0, 8192, stream);
  hipMemsetAsync(G, 0, 524288, stream);
  hipMemsetAsync(Abd, 0, 1048576, stream);

  convert_x<<<16384, 256, 0, stream>>>(x, x_bf);
  prep_w<<<1024, 256, 0, stream>>>(Wq, Wk, Wv, Wp, Wcat_t, Wp_t);

  // qkv = x_bf @ Wcat : M=32768 N=1536 K=512 (+ fused sumsq for q,k cols)
  gemm_lds<<<dim3(256, 12, 1), 256, 0, stream>>>(
      x_bf, Wcat_t, qkv, nullptr, ss, 512, 512, 1536, 512, 0L, 0L, 0L);

  gram_kernel<<<dim3(64, 4, 2), 256, 0, stream>>>(qkv, G);
  softmax_kernel<<<dim3(4, 2, 1), 256, 0, stream>>>(G, ss, rsc, Abd);

  // Mt[b] = Wp_t @ Abd[b]^T : M=512 N=512 K=512, batch 2
  gemm_lds<<<dim3(4, 4, 2), 256, 0, stream>>>(
      Wp_t, Abd, Mt, nullptr, nullptr, 512, 512, 512, 512, 0L, 262144L, 262144L);

  // out_c[b] = v @ Mt[b]^T + bp : M=16384 N=512 K=512, batch 2
  gemm_lds<<<dim3(128, 4, 2), 256, 0, stream>>>(
      qkv + 1024, Mt, out_c, bp, nullptr, 1536, 512, 512, 512,
      (long)16384 * 1536, 262144L, (long)16384 * 512);

  dwconv_kernel<true, false><<<dim3(16, 16, 2), 256, 0, stream>>>(
      qkv + 1024, 1536, pw1, nullptr, p1, nullptr);
  dwconv_kernel<false, true><<<dim3(16, 16, 2), 256, 0, stream>>>(
      p1, 512, pw2, out_c, nullptr, out);
}

// Round 3
// 409.590 us; speedup vs baseline: 1.1833x; 1.0180x over previous
//
#include <hip/hip_runtime.h>
#include <math.h>
#include <stdint.h>

// ---------------------------------------------------------------------------
// TransFrame: B=2, H=W=128, D=8, C=64 ; F_IN=F_OUT=512 ; HEADS=4, Dh=128
//   x_bf = bf16(x)                                  [32768 x 512]
//   Wcat_t = bf16([Wq|Wk|Wv]^T), Wp_t = bf16(Wp^T)  (LDS-tiled transpose)
//   qkv = x_bf @ Wcat (MFMA, global_load_lds staging)
//   gram: Gp[ns] partials (no atomics) + fused sumsq(q,k) -> ss
//   reduce_g: G = sum_ns Gp[ns]
//   softmax(G * rsqrt(ssk)*rsqrt(ssq)*rescale) -> Abd block-diagonal bf16
//   Mt[b] = Wp_t @ Abd[b]                           [512 x 512]
//   out_c[b] = v @ Mt[b]^T + bp                     [16384 x 512]
//   p1 = gelu(dwconv3(v, w1));  d_out = dwconv3(p1, w2) + out_c
// Epilogues use swapped-operand MFMA (acc holds transposed tile) so each
// lane's 4 acc regs are 4 consecutive n -> vectorized stores.
// ---------------------------------------------------------------------------

using short8  = __attribute__((ext_vector_type(8))) short;
using short4v = __attribute__((ext_vector_type(4))) short;
using f32x4   = __attribute__((ext_vector_type(4))) float;

__device__ __forceinline__ float bf2f(unsigned short u) {
  union { unsigned int i; float f; } v; v.i = ((unsigned int)u) << 16; return v.f;
}
__device__ __forceinline__ unsigned short f2bf(float f) {
  union { float f; unsigned int i; } v; v.f = f;
  unsigned int r = v.i + 0x7fffu + ((v.i >> 16) & 1u);
  return (unsigned short)(r >> 16);
}

// async global->LDS, 16B per lane. LDS dst is wave-uniform base + lane*16.
__device__ __forceinline__ void g2l16(const void* g, void* l) {
  __builtin_amdgcn_global_load_lds(
      (__attribute__((address_space(1))) void*)(unsigned long long)(uintptr_t)g,
      (__attribute__((address_space(3))) void*)(unsigned int)(uintptr_t)l,
      16, 0, 0);
}

// ---------------------------------------------------------------------------
__global__ __launch_bounds__(256) void convert_x(const float* __restrict__ x,
                                                 unsigned short* __restrict__ xb) {
  int i = (blockIdx.x * 256 + threadIdx.x) * 4;
  float4 v = *(const float4*)&x[i];
  ushort4 o;
  o.x = f2bf(v.x); o.y = f2bf(v.y); o.z = f2bf(v.z); o.w = f2bf(v.w);
  *(ushort4*)&xb[i] = o;
}

// LDS-tiled transpose of the 4 weight matrices (coalesced both sides).
__global__ __launch_bounds__(256) void prep_w(const float* __restrict__ Wq,
                                              const float* __restrict__ Wk,
                                              const float* __restrict__ Wv,
                                              const float* __restrict__ Wp,
                                              unsigned short* __restrict__ Wcat_t,
                                              unsigned short* __restrict__ Wp_t) {
  __shared__ unsigned short Ls[32 * 36];
  int bid = blockIdx.x;
  int mat = bid >> 8, tile = bid & 255;
  int tr = (tile >> 4) * 32, tc = (tile & 15) * 32;
  const float* src = (mat == 0) ? Wq : (mat == 1) ? Wk : (mat == 2) ? Wv : Wp;
  int t = threadIdx.x;
  int r = t >> 3, c4 = (t & 7) * 4;
  float4 v = *(const float4*)&src[(tr + r) * 512 + tc + c4];
  Ls[(c4 + 0) * 36 + r] = f2bf(v.x);
  Ls[(c4 + 1) * 36 + r] = f2bf(v.y);
  Ls[(c4 + 2) * 36 + r] = f2bf(v.z);
  Ls[(c4 + 3) * 36 + r] = f2bf(v.w);
  __syncthreads();
  int rn = t >> 3, ck4 = (t & 7) * 4;
  ushort4 o;
  o.x = Ls[rn * 36 + ck4 + 0]; o.y = Ls[rn * 36 + ck4 + 1];
  o.z = Ls[rn * 36 + ck4 + 2]; o.w = Ls[rn * 36 + ck4 + 3];
  unsigned short* dst = (mat < 3)
      ? &Wcat_t[(long)(mat * 512 + tc + rn) * 512 + tr + ck4]
      : &Wp_t[(long)(tc + rn) * 512 + tr + ck4];
  *(ushort4*)dst = o;
}

// ---------------------------------------------------------------------------
// bf16 MFMA GEMM, global_load_lds staging, XOR-swizzled BK=64 LDS.
// C[m][n] = sum_k A[m][k]*Bt[n][k] (+bias). n-tile on blockIdx.x (fastest)
// for L2 locality. Swapped-operand MFMA: acc[i][j][r] =
//   C[m0+wm*64+i*16+l16][n0+wn*64+j*16+quad*4+r]  -> uint2 bf16 stores.
// ---------------------------------------------------------------------------
__global__ __launch_bounds__(256) void gemm_lds(
    const unsigned short* __restrict__ A, const unsigned short* __restrict__ Bt,
    unsigned short* __restrict__ C, const float* __restrict__ bias,
    int lda, int ldb, int ldc, int K, long sA, long sB, long sC) {
  __shared__ unsigned short As[128 * 64];
  __shared__ unsigned short Bs[128 * 64];
  const int t = threadIdx.x;
  const int n0 = blockIdx.x * 128, m0 = blockIdx.y * 128;
  A  += (long)blockIdx.z * sA + (long)m0 * lda;
  Bt += (long)blockIdx.z * sB + (long)n0 * ldb;
  C  += (long)blockIdx.z * sC;
  const int lane = t & 63, w = t >> 6;
  const int wm = w >> 1, wn = w & 1;
  const int quad = lane >> 4, l16 = lane & 15;
  const int sr = lane >> 3;   // row within 8-row staging group
  const int sc = lane & 7;    // 16B slot within 128B row

  f32x4 acc[4][4] = {};

  for (int k0 = 0; k0 < K; k0 += 64) {
#pragma unroll
    for (int q = 0; q < 4; q++) {
      int r = q * 32 + w * 8 + sr;
      int ca = (sc ^ sr) * 8;
      g2l16(&A[(long)r * lda + k0 + ca], &As[(q * 32 + w * 8) * 64]);
      g2l16(&Bt[(long)r * ldb + k0 + ca], &Bs[(q * 32 + w * 8) * 64]);
    }
    __syncthreads();
#pragma unroll
    for (int kk = 0; kk < 2; kk++) {
      short8 af[4], bfq[4];
#pragma unroll
      for (int i = 0; i < 4; i++) {
        int r = wm * 64 + i * 16 + l16;
        int s = (kk * 4 + quad) ^ (r & 7);
        af[i] = *(const short8*)&As[r * 64 + s * 8];
      }
#pragma unroll
      for (int j = 0; j < 4; j++) {
        int r = wn * 64 + j * 16 + l16;
        int s = (kk * 4 + quad) ^ (r & 7);
        bfq[j] = *(const short8*)&Bs[r * 64 + s * 8];
      }
#pragma unroll
      for (int i = 0; i < 4; i++)
#pragma unroll
        for (int j = 0; j < 4; j++)
          acc[i][j] = __builtin_amdgcn_mfma_f32_16x16x32_bf16(bfq[j], af[i], acc[i][j], 0, 0, 0);
    }
    __syncthreads();
  }

#pragma unroll
  for (int i = 0; i < 4; i++) {
    long rbase = (long)(m0 + wm * 64 + i * 16 + l16) * ldc;
#pragma unroll
    for (int j = 0; j < 4; j++) {
      int col = n0 + wn * 64 + j * 16 + quad * 4;
      float b0 = 0.f, b1 = 0.f, b2 = 0.f, b3 = 0.f;
      if (bias) { float4 bv = *(const float4*)&bias[col]; b0 = bv.x; b1 = bv.y; b2 = bv.z; b3 = bv.w; }
      uint2 o;
      o.x = (unsigned)f2bf(acc[i][j][0] + b0) | ((unsigned)f2bf(acc[i][j][1] + b1) << 16);
      o.y = (unsigned)f2bf(acc[i][j][2] + b2) | ((unsigned)f2bf(acc[i][j][3] + b3) << 16);
      *(uint2*)&C[rbase + col] = o;
    }
  }
}

// ---------------------------------------------------------------------------
// Gram partials: Gp[ns][b,h][d][e] = sum_{n in split ns} k[d,n]*q[e,n]
// 32 splits of 512 n, 16 stages of 32. No atomics for G. Fused sumsq of
// q,k columns (post-bf16) -> atomicAdd ss (one per col per block).
// ---------------------------------------------------------------------------
__global__ __launch_bounds__(256) void gram_kernel(const unsigned short* __restrict__ qkv,
                                                   float* __restrict__ Gp,
                                                   float* __restrict__ ss) {
  __shared__ unsigned short Qs[128 * 36];
  __shared__ unsigned short Ks[128 * 36];
  int ns = blockIdx.x, h = blockIdx.y, b = blockIdx.z;
  int t = threadIdx.x;
  const int lane = t & 63, wave = t >> 6;
  const int wm = wave >> 1, wn = wave & 1;
  const int quad = lane >> 4, l16 = lane & 15;
  long base = (long)b * 16384 * 1536;
  // staging role
  int m = t >> 7;          // 0 = Q, 1 = K
  int tt = t & 127;
  int cg = tt & 31;        // col group of 4
  int rg = tt >> 5;        // n group of 8 (4 groups x 8 = 32 n/stage)
  int colb = (m ? (512 + h * 128) : (h * 128)) + cg * 4;
  unsigned short* dst = m ? Ks : Qs;

  f32x4 acc[4][4] = {};
  float ssp[4] = {0.f, 0.f, 0.f, 0.f};

  for (int s = 0; s < 16; s++) {
    int n0 = ns * 512 + s * 32;
    unsigned short sv[8][4];
#pragma unroll
    for (int rr = 0; rr < 8; rr++) {
      int n = n0 + rg * 8 + rr;
      uint2 v = *(const uint2*)&qkv[base + (long)n * 1536 + colb];
      sv[rr][0] = (unsigned short)(v.x & 0xffff);
      sv[rr][1] = (unsigned short)(v.x >> 16);
      sv[rr][2] = (unsigned short)(v.y & 0xffff);
      sv[rr][3] = (unsigned short)(v.y >> 16);
    }
#pragma unroll
    for (int rr = 0; rr < 8; rr++)
#pragma unroll
      for (int j = 0; j < 4; j++) {
        float fv = bf2f(sv[rr][j]);
        ssp[j] += fv * fv;
      }
#pragma unroll
    for (int j = 0; j < 4; j++) {
      int col = cg * 4 + j;
      ushort4 w0 = { sv[0][j], sv[1][j], sv[2][j], sv[3][j] };
      ushort4 w1 = { sv[4][j], sv[5][j], sv[6][j], sv[7][j] };
      *(ushort4*)&dst[col * 36 + rg * 8]     = w0;
      *(ushort4*)&dst[col * 36 + rg * 8 + 4] = w1;
    }
    __syncthreads();
    short8 af[4], bfq[4];
#pragma unroll
    for (int i = 0; i < 4; i++) {
      const unsigned short* p = &Ks[(wm * 64 + i * 16 + l16) * 36 + quad * 8];
      union { short8 v8; short4v v4[2]; } u;
      u.v4[0] = *(const short4v*)p; u.v4[1] = *(const short4v*)(p + 4);
      af[i] = u.v8;
    }
#pragma unroll
    for (int j = 0; j < 4; j++) {
      const unsigned short* p = &Qs[(wn * 64 + j * 16 + l16) * 36 + quad * 8];
      union { short8 v8; short4v v4[2]; } u;
      u.v4[0] = *(const short4v*)p; u.v4[1] = *(const short4v*)(p + 4);
      bfq[j] = u.v8;
    }
#pragma unroll
    for (int i = 0; i < 4; i++)
#pragma unroll
      for (int j = 0; j < 4; j++)
        acc[i][j] = __builtin_amdgcn_mfma_f32_16x16x32_bf16(bfq[j], af[i], acc[i][j], 0, 0, 0);
    __syncthreads();
  }

  // Gp store: swapped layout -> acc[i][j][r] = G[d=wm*64+i*16+l16][e=wn*64+j*16+quad*4+r]
  float* gp = Gp + ((long)ns * 8 + b * 4 + h) * 16384;
#pragma unroll
  for (int i = 0; i < 4; i++) {
    int row = wm * 64 + i * 16 + l16;
#pragma unroll
    for (int j = 0; j < 4; j++) {
      int col = wn * 64 + j * 16 + quad * 4;
      *(f32x4*)&gp[row * 128 + col] = acc[i][j];
    }
  }

  // ss reduce: partials per (m, col=cg*4+j) across 4 rg groups
  float* sred = (float*)Qs;  // 256 cols x 5 floats = 5120 B
#pragma unroll
  for (int j = 0; j < 4; j++) sred[(m * 128 + cg * 4 + j) * 5 + rg] = ssp[j];
  __syncthreads();
  {
    float s = sred[t * 5 + 0] + sred[t * 5 + 1] + sred[t * 5 + 2] + sred[t * 5 + 3];
    int m2 = t >> 7, col = t & 127;
    atomicAdd(&ss[b * 1024 + m2 * 512 + h * 128 + col], s);
  }
}

// G = sum over 32 splits of Gp
__global__ __launch_bounds__(256) void reduce_g(const float* __restrict__ Gp,
                                                float* __restrict__ G) {
  int i = blockIdx.x * 256 + threadIdx.x;
  float s = 0.f;
#pragma unroll 8
  for (int ns = 0; ns < 32; ns++) s += Gp[(long)ns * 131072 + i];
  G[i] = s;
}

// ---------------------------------------------------------------------------
// softmax over e of scaled G; writes block-diagonal Abd (bf16, rest zeroed).
// ---------------------------------------------------------------------------
__global__ __launch_bounds__(256) void softmax_kernel(const float* __restrict__ G,
                                                      const float* __restrict__ ss,
                                                      const float* __restrict__ rescale,
                                                      unsigned short* __restrict__ Abd) {
  __shared__ float L[128 * 129];
  __shared__ float rsq[128];
  __shared__ float rsk[128];
  int h = blockIdx.x, b = blockIdx.y;
  int t = threadIdx.x;
  const float* g = G + (long)(b * 4 + h) * 16384;
  if (t < 128) rsq[t] = rsqrtf(fmaxf(ss[b * 1024 + h * 128 + t], 1e-24f));
  else { int d = t - 128; rsk[d] = rsqrtf(fmaxf(ss[b * 1024 + 512 + h * 128 + d], 1e-24f)); }
  __syncthreads();
  float rs = rescale[h];
  for (int i = t; i < 16384; i += 256) {
    int d = i >> 7, e = i & 127;
    L[d * 129 + e] = g[i] * rsk[d] * rsq[e] * rs;
  }
  __syncthreads();
  if (t < 128) {
    float* row = &L[t * 129];
    float mx = -1e30f;
    for (int e = 0; e < 128; e++) mx = fmaxf(mx, row[e]);
    float sum = 0.0f;
    for (int e = 0; e < 128; e++) { float ex = __expf(row[e] - mx); row[e] = ex; sum += ex; }
    float inv = 1.0f / sum;
    long abase = (long)b * 262144;
    for (int e = 0; e < 128; e++)
      Abd[abase + (long)(h * 128 + e) * 512 + h * 128 + t] = f2bf(row[e] * inv);
  }
}

// ---------------------------------------------------------------------------
// depthwise 3x3x3 conv over (d,h,w); feature f = d*64+c.
// ---------------------------------------------------------------------------
template <bool GELU, bool ADD>
__global__ __launch_bounds__(256) void dwconv_kernel(
    const unsigned short* __restrict__ in, int inld,
    const float* __restrict__ wgt,
    const unsigned short* __restrict__ addc,
    unsigned short* __restrict__ outb,
    float* __restrict__ outf) {
  __shared__ unsigned short tile[100 * 512];
  __shared__ float wl[27 * 64];
  int wt = blockIdx.x, ht = blockIdx.y, b = blockIdx.z;
  int t = threadIdx.x;
  for (int i = t; i < 1728; i += 256) {
    int c = i / 27, tap = i % 27;
    wl[tap * 64 + c] = wgt[i];
  }
  int h0 = ht * 8, w0 = wt * 8;
  int lg = t & 63;
#pragma unroll 5
  for (int rr = 0; rr < 25; rr++) {
    int row = rr * 4 + (t >> 6);
    int hh = row / 10, ww = row % 10;
    int gh = h0 + hh - 1, gw = w0 + ww - 1;
    uint4 v = {0u, 0u, 0u, 0u};
    if ((unsigned)gh < 128u && (unsigned)gw < 128u)
      v = *(const uint4*)&in[(long)(b * 16384 + gh * 128 + gw) * inld + lg * 8];
    *(uint4*)&tile[row * 512 + lg * 8] = v;
  }
  __syncthreads();

  int f0 = lg * 8;
  int d = f0 >> 6, c0 = f0 & 63;
  int pg = t >> 6;
  for (int P = 0; P < 4; P++) {
    float acc[4][8] = {};
    for (int kd = 0; kd < 3; kd++) {
      int dz = d + kd - 1;
      if ((unsigned)dz >= 8u) continue;
      int fz = dz * 64 + c0;
#pragma unroll
      for (int kh = 0; kh < 3; kh++)
#pragma unroll
        for (int kw = 0; kw < 3; kw++) {
          int tap = kd * 9 + kh * 3 + kw;
          float w[8];
          *(float4*)&w[0] = *(const float4*)&wl[tap * 64 + c0];
          *(float4*)&w[4] = *(const float4*)&wl[tap * 64 + c0 + 4];
#pragma unroll
          for (int s = 0; s < 4; s++) {
            int pos = P * 16 + pg * 4 + s;
            int ph = pos >> 3, pw = pos & 7;
            uint4 pv = *(const uint4*)&tile[((ph + kh) * 10 + pw + kw) * 512 + fz];
            const unsigned short* u = (const unsigned short*)&pv;
#pragma unroll
            for (int j = 0; j < 8; j++) acc[s][j] += bf2f(u[j]) * w[j];
          }
        }
    }
    for (int s = 0; s < 4; s++) {
      int pos = P * 16 + pg * 4 + s;
      int ph = pos >> 3, pw = pos & 7;
      long row = (long)(b * 16384 + (h0 + ph) * 128 + (w0 + pw));
      if (GELU) {
        unsigned short o[8];
#pragma unroll
        for (int j = 0; j < 8; j++) {
          float x = acc[s][j];
          o[j] = f2bf(0.5f * x * (1.0f + erff(x * 0.70710678118654752f)));
        }
        *(uint4*)&outb[row * 512 + f0] = *(uint4*)&o[0];
      } else {
        uint4 av = *(const uint4*)&addc[row * 512 + f0];
        const unsigned short* au = (const unsigned short*)&av;
        float o[8];
#pragma unroll
        for (int j = 0; j < 8; j++) o[j] = acc[s][j] + bf2f(au[j]);
        *(float4*)&outf[row * 512 + f0]     = *(float4*)&o[0];
        *(float4*)&outf[row * 512 + f0 + 4] = *(float4*)&o[4];
      }
    }
  }
}

// ---------------------------------------------------------------------------
extern "C" void kernel_launch(void* const* d_in, const int* in_sizes, int n_in,
                              void* d_out, int out_size, void* d_ws, size_t ws_size,
                              hipStream_t stream) {
  const float* x   = (const float*)d_in[0];
  const float* Wq  = (const float*)d_in[1];
  const float* Wk  = (const float*)d_in[2];
  const float* Wv  = (const float*)d_in[3];
  const float* rsc = (const float*)d_in[4];
  const float* Wp  = (const float*)d_in[5];
  const float* bp  = (const float*)d_in[6];
  const float* pw1 = (const float*)d_in[7];
  const float* pw2 = (const float*)d_in[8];
  float* out = (float*)d_out;

  char* ws = (char*)d_ws;
  unsigned short* x_bf   = (unsigned short*)(ws + 0);           // 33,554,432
  unsigned short* qkv    = (unsigned short*)(ws + 33554432);    // 100,663,296
  unsigned short* Wcat_t = (unsigned short*)(ws + 134217728);   // 1,572,864
  unsigned short* Wp_t   = (unsigned short*)(ws + 135790592);   // 524,288
  float*          ss     = (float*)(ws + 136314880);            // 8,192
  float*          G      = (float*)(ws + 136323072);            // 524,288
  unsigned short* Abd    = (unsigned short*)(ws + 136847360);   // 1,048,576
  unsigned short* Mt     = (unsigned short*)(ws + 137895936);   // 1,048,576
  unsigned short* out_c  = (unsigned short*)(ws + 138944512);   // 33,554,432
  // Gp (16.8 MB) overlays x_bf region: x_bf dead after QKV GEMM, Gp dead
  // before dwconv1 writes p1 (= x_bf). Same stream => sequential, safe.
  float*          Gp     = (float*)(ws + 0);
  unsigned short* p1     = x_bf;

  hipMemsetAsync(ss, 0, 8192, stream);
  hipMemsetAsync(Abd, 0, 1048576, stream);

  convert_x<<<16384, 256, 0, stream>>>(x, x_bf);
  prep_w<<<1024, 256, 0, stream>>>(Wq, Wk, Wv, Wp, Wcat_t, Wp_t);

  // qkv = x_bf @ Wcat : M=32768 N=1536 K=512  (grid x = n-tiles for L2 reuse)
  gemm_lds<<<dim3(12, 256, 1), 256, 0, stream>>>(
      x_bf, Wcat_t, qkv, nullptr, 512, 512, 1536, 512, 0L, 0L, 0L);

  // Gram partials + fused sumsq
  gram_kernel<<<dim3(32, 4, 2), 256, 0, stream>>>(qkv, Gp, ss);
  reduce_g<<<512, 256, 0, stream>>>(Gp, G);
  softmax_kernel<<<dim3(4, 2, 1), 256, 0, stream>>>(G, ss, rsc, Abd);

  // Mt[b] = Wp_t @ Abd[b]^T : M=512 N=512 K=512, batch 2
  gemm_lds<<<dim3(4, 4, 2), 256, 0, stream>>>(
      Wp_t, Abd, Mt, nullptr, 512, 512, 512, 512, 0L, 262144L, 262144L);

  // out_c[b] = v @ Mt[b]^T + bp : M=16384 N=512 K=512, batch 2
  gemm_lds<<<dim3(4, 128, 2), 256, 0, stream>>>(
      qkv + 1024, Mt, out_c, bp, 1536, 512, 512, 512,
      (long)16384 * 1536, 262144L, (long)16384 * 512);

  dwconv_kernel<true, false><<<dim3(16, 16, 2), 256, 0, stream>>>(
      qkv + 1024, 1536, pw1, nullptr, p1, nullptr);
  dwconv_kernel<false, true><<<dim3(16, 16, 2), 256, 0, stream>>>(
      p1, 512, pw2, out_c, nullptr, out);
}

// Round 4
// 383.948 us; speedup vs baseline: 1.2623x; 1.0668x over previous
//
#include <hip/hip_runtime.h>
#include <math.h>
#include <stdint.h>

// ---------------------------------------------------------------------------
// TransFrame: B=2, H=W=128, D=8, C=64 ; F_IN=F_OUT=512 ; HEADS=4, Dh=128
//   x_bf = bf16(x)                                  [32768 x 512]
//   fused_qkv (grid 8 jobs x 128 mt x 2 b):
//     jobs 0-3 (head h): q,k 128x128 tiles (K=512) -> LDS transpose ->
//       gram partial Gt_p[d?e] over 128 spatial (MFMA, spatial=K) -> Gp
//       + sumsq(q,k) from acc regs -> ss (atomic, 256/block)
//       q,k NEVER written to HBM.
//     jobs 4-7: v n-tile, written to compact v [32768x512]
//   reduce_g: G(t) = sum_mt Gp   (67 MB partials, non-atomic)
//   softmax(Gt * scales) -> Abd block-diagonal bf16
//   Mt[b] = Wp_t @ Abd[b]^T ;  out_c[b] = v @ Mt[b]^T + bp
//   p1 = gelu(dwconv3(v, w1));  d_out = dwconv3(p1, w2) + out_c
// ---------------------------------------------------------------------------

using short8  = __attribute__((ext_vector_type(8))) short;
using f32x4   = __attribute__((ext_vector_type(4))) float;

__device__ __forceinline__ float bf2f(unsigned short u) {
  union { unsigned int i; float f; } v; v.i = ((unsigned int)u) << 16; return v.f;
}
__device__ __forceinline__ unsigned short f2bf(float f) {
  union { float f; unsigned int i; } v; v.f = f;
  unsigned int r = v.i + 0x7fffu + ((v.i >> 16) & 1u);
  return (unsigned short)(r >> 16);
}

__device__ __forceinline__ void g2l16(const void* g, void* l) {
  __builtin_amdgcn_global_load_lds(
      (__attribute__((address_space(1))) void*)(unsigned long long)(uintptr_t)g,
      (__attribute__((address_space(3))) void*)(unsigned int)(uintptr_t)l,
      16, 0, 0);
}

// ---------------------------------------------------------------------------
__global__ __launch_bounds__(256) void convert_x(const float* __restrict__ x,
                                                 unsigned short* __restrict__ xb) {
  int i = (blockIdx.x * 256 + threadIdx.x) * 4;
  float4 v = *(const float4*)&x[i];
  ushort4 o;
  o.x = f2bf(v.x); o.y = f2bf(v.y); o.z = f2bf(v.z); o.w = f2bf(v.w);
  *(ushort4*)&xb[i] = o;
}

__global__ __launch_bounds__(256) void prep_w(const float* __restrict__ Wq,
                                              const float* __restrict__ Wk,
                                              const float* __restrict__ Wv,
                                              const float* __restrict__ Wp,
                                              unsigned short* __restrict__ Wcat_t,
                                              unsigned short* __restrict__ Wp_t) {
  __shared__ unsigned short Ls[32 * 36];
  int bid = blockIdx.x;
  int mat = bid >> 8, tile = bid & 255;
  int tr = (tile >> 4) * 32, tc = (tile & 15) * 32;
  const float* src = (mat == 0) ? Wq : (mat == 1) ? Wk : (mat == 2) ? Wv : Wp;
  int t = threadIdx.x;
  int r = t >> 3, c4 = (t & 7) * 4;
  float4 v = *(const float4*)&src[(tr + r) * 512 + tc + c4];
  Ls[(c4 + 0) * 36 + r] = f2bf(v.x);
  Ls[(c4 + 1) * 36 + r] = f2bf(v.y);
  Ls[(c4 + 2) * 36 + r] = f2bf(v.z);
  Ls[(c4 + 3) * 36 + r] = f2bf(v.w);
  __syncthreads();
  int rn = t >> 3, ck4 = (t & 7) * 4;
  ushort4 o;
  o.x = Ls[rn * 36 + ck4 + 0]; o.y = Ls[rn * 36 + ck4 + 1];
  o.z = Ls[rn * 36 + ck4 + 2]; o.w = Ls[rn * 36 + ck4 + 3];
  unsigned short* dst = (mat < 3)
      ? &Wcat_t[(long)(mat * 512 + tc + rn) * 512 + tr + ck4]
      : &Wp_t[(long)(tc + rn) * 512 + tr + ck4];
  *(ushort4*)dst = o;
}

// ---------------------------------------------------------------------------
// fused qkv + gram + sumsq. grid (job=8, mt=128, b=2), 256 thr.
// jobs 0-3: head h=job -> q,k tiles + gram partial + sumsq (no HBM q,k)
// jobs 4-7: v n-tile (job-4), swapped-operand epilogue, uint2 stores.
// ---------------------------------------------------------------------------
__global__ __launch_bounds__(256, 2) void fused_qkv(
    const unsigned short* __restrict__ x_bf,
    const unsigned short* __restrict__ Wcat_t,
    unsigned short* __restrict__ v,
    float* __restrict__ Gp, float* __restrict__ ss) {
  __shared__ unsigned short sh[38912];   // 77,824 B
  unsigned short* As = sh;               // 8192 shorts (128x64)
  unsigned short* B0 = sh + 8192;        // 8192
  unsigned short* B1 = sh + 16384;       // 8192
  const int job = blockIdx.x, mt = blockIdx.y, b = blockIdx.z;
  const int t = threadIdx.x;
  const int lane = t & 63, w = t >> 6;
  const int wm = w >> 1, wn = w & 1;
  const int quad = lane >> 4, l16 = lane & 15;
  const int sr = lane >> 3, sc = lane & 7;
  const unsigned short* A = x_bf + ((long)b * 16384 + mt * 128) * 512;

  if (job >= 4) {
    // ---- v n-tile ----
    const unsigned short* Bt = Wcat_t + (long)(1024 + (job - 4) * 128) * 512;
    f32x4 acc[4][4] = {};
    for (int k0 = 0; k0 < 512; k0 += 64) {
#pragma unroll
      for (int q = 0; q < 4; q++) {
        int r = q * 32 + w * 8 + sr;
        int ca = (sc ^ sr) * 8;
        g2l16(&A[(long)r * 512 + k0 + ca], &As[(q * 32 + w * 8) * 64]);
        g2l16(&Bt[(long)r * 512 + k0 + ca], &B0[(q * 32 + w * 8) * 64]);
      }
      __syncthreads();
#pragma unroll
      for (int kk = 0; kk < 2; kk++) {
        short8 af[4], bf[4];
#pragma unroll
        for (int i = 0; i < 4; i++) {
          int r = wm * 64 + i * 16 + l16;
          int s = (kk * 4 + quad) ^ (r & 7);
          af[i] = *(const short8*)&As[r * 64 + s * 8];
        }
#pragma unroll
        for (int j = 0; j < 4; j++) {
          int r = wn * 64 + j * 16 + l16;
          int s = (kk * 4 + quad) ^ (r & 7);
          bf[j] = *(const short8*)&B0[r * 64 + s * 8];
        }
#pragma unroll
        for (int i = 0; i < 4; i++)
#pragma unroll
          for (int j = 0; j < 4; j++)
            acc[i][j] = __builtin_amdgcn_mfma_f32_16x16x32_bf16(bf[j], af[i], acc[i][j], 0, 0, 0);
      }
      __syncthreads();
    }
    unsigned short* vout = v + ((long)b * 16384 + mt * 128) * 512 + (job - 4) * 128;
#pragma unroll
    for (int i = 0; i < 4; i++) {
      long rbase = (long)(wm * 64 + i * 16 + l16) * 512;
#pragma unroll
      for (int j = 0; j < 4; j++) {
        int col = wn * 64 + j * 16 + quad * 4;
        uint2 o;
        o.x = (unsigned)f2bf(acc[i][j][0]) | ((unsigned)f2bf(acc[i][j][1]) << 16);
        o.y = (unsigned)f2bf(acc[i][j][2]) | ((unsigned)f2bf(acc[i][j][3]) << 16);
        *(uint2*)&vout[rbase + col] = o;
      }
    }
  } else {
    // ---- q,k + gram + sumsq for head h ----
    const int h = job;
    const unsigned short* Bq = Wcat_t + (long)(h * 128) * 512;
    const unsigned short* Bk = Wcat_t + (long)(512 + h * 128) * 512;
    f32x4 aq[4][4] = {}, ak[4][4] = {};
    for (int k0 = 0; k0 < 512; k0 += 64) {
#pragma unroll
      for (int q = 0; q < 4; q++) {
        int r = q * 32 + w * 8 + sr;
        int ca = (sc ^ sr) * 8;
        g2l16(&A[(long)r * 512 + k0 + ca],  &As[(q * 32 + w * 8) * 64]);
        g2l16(&Bq[(long)r * 512 + k0 + ca], &B0[(q * 32 + w * 8) * 64]);
        g2l16(&Bk[(long)r * 512 + k0 + ca], &B1[(q * 32 + w * 8) * 64]);
      }
      __syncthreads();
#pragma unroll
      for (int kk = 0; kk < 2; kk++) {
        short8 af[4], bq[4], bk[4];
#pragma unroll
        for (int i = 0; i < 4; i++) {
          int r = wm * 64 + i * 16 + l16;
          int s = (kk * 4 + quad) ^ (r & 7);
          af[i] = *(const short8*)&As[r * 64 + s * 8];
        }
#pragma unroll
        for (int j = 0; j < 4; j++) {
          int r = wn * 64 + j * 16 + l16;
          int s = (kk * 4 + quad) ^ (r & 7);
          bq[j] = *(const short8*)&B0[r * 64 + s * 8];
          bk[j] = *(const short8*)&B1[r * 64 + s * 8];
        }
#pragma unroll
        for (int i = 0; i < 4; i++)
#pragma unroll
          for (int j = 0; j < 4; j++) {
            aq[i][j] = __builtin_amdgcn_mfma_f32_16x16x32_bf16(af[i], bq[j], aq[i][j], 0, 0, 0);
            ak[i][j] = __builtin_amdgcn_mfma_f32_16x16x32_bf16(af[i], bk[j], ak[i][j], 0, 0, 0);
          }
      }
      __syncthreads();
    }
    // epilogue: acc layout (std order): aq[i][j][r] = q[m=wm*64+i*16+quad*4+r][f=wn*64+j*16+l16]
    unsigned short* kT = sh;           // 128 x 136
    unsigned short* qT = sh + 17408;   // 128 x 136
    float* red = (float*)(sh + 34816); // 2048 floats: [0..1023]=q, [1024..]=k
#pragma unroll
    for (int i = 0; i < 4; i++) {
      int mm = wm * 64 + i * 16 + quad * 4;
#pragma unroll
      for (int j = 0; j < 4; j++) {
        int f = wn * 64 + j * 16 + l16;
        ushort4 oq = { f2bf(aq[i][j][0]), f2bf(aq[i][j][1]), f2bf(aq[i][j][2]), f2bf(aq[i][j][3]) };
        ushort4 ok = { f2bf(ak[i][j][0]), f2bf(ak[i][j][1]), f2bf(ak[i][j][2]), f2bf(ak[i][j][3]) };
        *(ushort4*)&qT[f * 136 + mm] = oq;
        *(ushort4*)&kT[f * 136 + mm] = ok;
      }
    }
    // sumsq partials (pre-rounding fp32 acc)
    int grp = wm * 4 + quad;
#pragma unroll
    for (int j = 0; j < 4; j++) {
      float pq = 0.f, pk = 0.f;
#pragma unroll
      for (int i = 0; i < 4; i++)
#pragma unroll
        for (int r = 0; r < 4; r++) { pq += aq[i][j][r] * aq[i][j][r]; pk += ak[i][j][r] * ak[i][j][r]; }
      int col = wn * 64 + j * 16 + l16;
      red[grp * 128 + col] = pq;
      red[1024 + grp * 128 + col] = pk;
    }
    __syncthreads();
    // gram: G[d][e] = sum_m kT[d][m]*qT[e][m], m=0..127 (4 chunks of 32)
    f32x4 g[4][4] = {};
#pragma unroll
    for (int kk2 = 0; kk2 < 4; kk2++) {
      short8 afk[4], bfq[4];
#pragma unroll
      for (int i = 0; i < 4; i++)
        afk[i] = *(const short8*)&kT[(wm * 64 + i * 16 + l16) * 136 + kk2 * 32 + quad * 8];
#pragma unroll
      for (int j = 0; j < 4; j++)
        bfq[j] = *(const short8*)&qT[(wn * 64 + j * 16 + l16) * 136 + kk2 * 32 + quad * 8];
#pragma unroll
      for (int i = 0; i < 4; i++)
#pragma unroll
        for (int j = 0; j < 4; j++)
          g[i][j] = __builtin_amdgcn_mfma_f32_16x16x32_bf16(afk[i], bfq[j], g[i][j], 0, 0, 0);
    }
    // store transposed partial: Gt[e][d] (d consecutive in lane -> f32x4)
    float* gp = Gp + (((long)(b * 128 + mt) * 4 + h) << 14);
#pragma unroll
    for (int i = 0; i < 4; i++) {
      int dd = wm * 64 + i * 16 + quad * 4;
#pragma unroll
      for (int j = 0; j < 4; j++) {
        int e = wn * 64 + j * 16 + l16;
        *(f32x4*)&gp[e * 128 + dd] = g[i][j];
      }
    }
    // finish sumsq
    {
      int sel = t >> 7, col = t & 127;
      float s = 0.f;
#pragma unroll
      for (int g2 = 0; g2 < 8; g2++) s += red[sel * 1024 + g2 * 128 + col];
      atomicAdd(&ss[b * 1024 + sel * 512 + h * 128 + col], s);
    }
  }
}

// G(t)[b,h][e][d] = sum over 128 m-tiles of Gp
__global__ __launch_bounds__(256) void reduce_g(const float* __restrict__ Gp,
                                                float* __restrict__ G) {
  int i = blockIdx.x * 256 + threadIdx.x;
  int b = i >> 16, h = (i >> 14) & 3, r = i & 16383;
  const float* p = Gp + (((long)b * 512 + h) << 14) + r;
  float s = 0.f;
#pragma unroll 8
  for (int mtv = 0; mtv < 128; mtv++) s += p[(long)mtv * 65536];
  G[i] = s;
}

// ---------------------------------------------------------------------------
// softmax over e of scaled G (input is Gt[e][d]); writes block-diag Abd.
// ---------------------------------------------------------------------------
__global__ __launch_bounds__(256) void softmax_kernel(const float* __restrict__ Gt,
                                                      const float* __restrict__ ss,
                                                      const float* __restrict__ rescale,
                                                      unsigned short* __restrict__ Abd) {
  __shared__ float L[128 * 129];
  __shared__ float rsq[128];
  __shared__ float rsk[128];
  int h = blockIdx.x, b = blockIdx.y;
  int t = threadIdx.x;
  const float* g = Gt + (long)(b * 4 + h) * 16384;
  if (t < 128) rsq[t] = rsqrtf(fmaxf(ss[b * 1024 + h * 128 + t], 1e-24f));
  else { int d = t - 128; rsk[d] = rsqrtf(fmaxf(ss[b * 1024 + 512 + h * 128 + d], 1e-24f)); }
  __syncthreads();
  float rs = rescale[h];
  for (int i = t; i < 16384; i += 256) {
    int e = i >> 7, d = i & 127;           // Gt is e-major
    L[d * 129 + e] = g[i] * rsk[d] * rsq[e] * rs;
  }
  __syncthreads();
  if (t < 128) {
    float* row = &L[t * 129];
    float mx = -1e30f;
    for (int e = 0; e < 128; e++) mx = fmaxf(mx, row[e]);
    float sum = 0.0f;
    for (int e = 0; e < 128; e++) { float ex = __expf(row[e] - mx); row[e] = ex; sum += ex; }
    float inv = 1.0f / sum;
    long abase = (long)b * 262144;
    for (int e = 0; e < 128; e++)
      Abd[abase + (long)(h * 128 + e) * 512 + h * 128 + t] = f2bf(row[e] * inv);
  }
}

// ---------------------------------------------------------------------------
// generic bf16 GEMM (round-3 proven): C=A@Bt^T (+bias), swapped epilogue.
// ---------------------------------------------------------------------------
__global__ __launch_bounds__(256) void gemm_lds(
    const unsigned short* __restrict__ A, const unsigned short* __restrict__ Bt,
    unsigned short* __restrict__ C, const float* __restrict__ bias,
    int lda, int ldb, int ldc, int K, long sA, long sB, long sC) {
  __shared__ unsigned short As[128 * 64];
  __shared__ unsigned short Bs[128 * 64];
  const int t = threadIdx.x;
  const int n0 = blockIdx.x * 128, m0 = blockIdx.y * 128;
  A  += (long)blockIdx.z * sA + (long)m0 * lda;
  Bt += (long)blockIdx.z * sB + (long)n0 * ldb;
  C  += (long)blockIdx.z * sC;
  const int lane = t & 63, w = t >> 6;
  const int wm = w >> 1, wn = w & 1;
  const int quad = lane >> 4, l16 = lane & 15;
  const int sr = lane >> 3, sc = lane & 7;

  f32x4 acc[4][4] = {};

  for (int k0 = 0; k0 < K; k0 += 64) {
#pragma unroll
    for (int q = 0; q < 4; q++) {
      int r = q * 32 + w * 8 + sr;
      int ca = (sc ^ sr) * 8;
      g2l16(&A[(long)r * lda + k0 + ca], &As[(q * 32 + w * 8) * 64]);
      g2l16(&Bt[(long)r * ldb + k0 + ca], &Bs[(q * 32 + w * 8) * 64]);
    }
    __syncthreads();
#pragma unroll
    for (int kk = 0; kk < 2; kk++) {
      short8 af[4], bfq[4];
#pragma unroll
      for (int i = 0; i < 4; i++) {
        int r = wm * 64 + i * 16 + l16;
        int s = (kk * 4 + quad) ^ (r & 7);
        af[i] = *(const short8*)&As[r * 64 + s * 8];
      }
#pragma unroll
      for (int j = 0; j < 4; j++) {
        int r = wn * 64 + j * 16 + l16;
        int s = (kk * 4 + quad) ^ (r & 7);
        bfq[j] = *(const short8*)&Bs[r * 64 + s * 8];
      }
#pragma unroll
      for (int i = 0; i < 4; i++)
#pragma unroll
        for (int j = 0; j < 4; j++)
          acc[i][j] = __builtin_amdgcn_mfma_f32_16x16x32_bf16(bfq[j], af[i], acc[i][j], 0, 0, 0);
    }
    __syncthreads();
  }

#pragma unroll
  for (int i = 0; i < 4; i++) {
    long rbase = (long)(m0 + wm * 64 + i * 16 + l16) * ldc;
#pragma unroll
    for (int j = 0; j < 4; j++) {
      int col = n0 + wn * 64 + j * 16 + quad * 4;
      float b0 = 0.f, b1 = 0.f, b2 = 0.f, b3 = 0.f;
      if (bias) { float4 bv = *(const float4*)&bias[col]; b0 = bv.x; b1 = bv.y; b2 = bv.z; b3 = bv.w; }
      uint2 o;
      o.x = (unsigned)f2bf(acc[i][j][0] + b0) | ((unsigned)f2bf(acc[i][j][1] + b1) << 16);
      o.y = (unsigned)f2bf(acc[i][j][2] + b2) | ((unsigned)f2bf(acc[i][j][3] + b3) << 16);
      *(uint2*)&C[rbase + col] = o;
    }
  }
}

// ---------------------------------------------------------------------------
// depthwise 3x3x3 conv; 8x4 spatial tile, 68 KB LDS (2 blocks/CU),
// register-reuse inner loop (6 loads/48 cvt per tap-row instead of 12/96).
// ---------------------------------------------------------------------------
template <bool GELU>
__global__ __launch_bounds__(256) void dwconv_kernel(
    const unsigned short* __restrict__ in,
    const float* __restrict__ wgt,
    const unsigned short* __restrict__ addc,
    unsigned short* __restrict__ outb,
    float* __restrict__ outf) {
  __shared__ unsigned short tile[60 * 512];
  __shared__ float wl[27 * 64];
  int wt = blockIdx.x, ht = blockIdx.y, b = blockIdx.z;
  int t = threadIdx.x;
  for (int i = t; i < 1728; i += 256) {
    int c = i / 27, tap = i % 27;
    wl[tap * 64 + c] = wgt[i];
  }
  int h0 = ht * 4, w0 = wt * 8;
  int lg = t & 63;
#pragma unroll 5
  for (int rr = 0; rr < 15; rr++) {
    int row = rr * 4 + (t >> 6);
    int hh = row / 10, ww = row % 10;
    int gh = h0 + hh - 1, gw = w0 + ww - 1;
    uint4 vv = {0u, 0u, 0u, 0u};
    if ((unsigned)gh < 128u && (unsigned)gw < 128u)
      vv = *(const uint4*)&in[((long)(b * 16384 + gh * 128 + gw)) * 512 + lg * 8];
    *(uint4*)&tile[row * 512 + lg * 8] = vv;
  }
  __syncthreads();

  int f0 = lg * 8;
  int d = f0 >> 6, c0 = f0 & 63;
  int pg = t >> 6;
  int pwb = (pg & 1) * 4;
#pragma unroll
  for (int P = 0; P < 2; P++) {
    int ph = P * 2 + (pg >> 1);
    float acc[4][8] = {};
    for (int kd = 0; kd < 3; kd++) {
      int dz = d + kd - 1;
      if ((unsigned)dz >= 8u) continue;
      int fz = dz * 64 + c0;
#pragma unroll
      for (int kh = 0; kh < 3; kh++) {
        float tf[6][8];
#pragma unroll
        for (int cc = 0; cc < 6; cc++) {
          uint4 pv = *(const uint4*)&tile[((ph + kh) * 10 + pwb + cc) * 512 + fz];
          const unsigned short* u = (const unsigned short*)&pv;
#pragma unroll
          for (int j = 0; j < 8; j++) tf[cc][j] = bf2f(u[j]);
        }
#pragma unroll
        for (int kw = 0; kw < 3; kw++) {
          int tap = kd * 9 + kh * 3 + kw;
          float wv[8];
          *(float4*)&wv[0] = *(const float4*)&wl[tap * 64 + c0];
          *(float4*)&wv[4] = *(const float4*)&wl[tap * 64 + c0 + 4];
#pragma unroll
          for (int s = 0; s < 4; s++)
#pragma unroll
            for (int j = 0; j < 8; j++) acc[s][j] += tf[s + kw][j] * wv[j];
        }
      }
    }
#pragma unroll
    for (int s = 0; s < 4; s++) {
      int pw = pwb + s;
      long row = (long)(b * 16384 + (h0 + ph) * 128 + (w0 + pw));
      if (GELU) {
        unsigned short o[8];
#pragma unroll
        for (int j = 0; j < 8; j++) {
          float xg = acc[s][j];
          o[j] = f2bf(0.5f * xg * (1.0f + erff(xg * 0.70710678118654752f)));
        }
        *(uint4*)&outb[row * 512 + f0] = *(uint4*)&o[0];
      } else {
        uint4 av = *(const uint4*)&addc[row * 512 + f0];
        const unsigned short* au = (const unsigned short*)&av;
        float o[8];
#pragma unroll
        for (int j = 0; j < 8; j++) o[j] = acc[s][j] + bf2f(au[j]);
        *(float4*)&outf[row * 512 + f0]     = *(float4*)&o[0];
        *(float4*)&outf[row * 512 + f0 + 4] = *(float4*)&o[4];
      }
    }
  }
}

// ---------------------------------------------------------------------------
extern "C" void kernel_launch(void* const* d_in, const int* in_sizes, int n_in,
                              void* d_out, int out_size, void* d_ws, size_t ws_size,
                              hipStream_t stream) {
  const float* x   = (const float*)d_in[0];
  const float* Wq  = (const float*)d_in[1];
  const float* Wk  = (const float*)d_in[2];
  const float* Wv  = (const float*)d_in[3];
  const float* rsc = (const float*)d_in[4];
  const float* Wp  = (const float*)d_in[5];
  const float* bp  = (const float*)d_in[6];
  const float* pw1 = (const float*)d_in[7];
  const float* pw2 = (const float*)d_in[8];
  float* out = (float*)d_out;

  char* ws = (char*)d_ws;
  unsigned short* x_bf   = (unsigned short*)(ws + 0);            // 33,554,432
  unsigned short* v      = (unsigned short*)(ws + 33554432);     // 33,554,432
  unsigned short* out_c  = (unsigned short*)(ws + 67108864);     // 33,554,432
  float*          Gp     = (float*)(ws + 100663296);             // 67,108,864
  unsigned short* Wcat_t = (unsigned short*)(ws + 167772160);    // 1,572,864
  unsigned short* Wp_t   = (unsigned short*)(ws + 169345024);    // 524,288
  float*          ss     = (float*)(ws + 169869312);             // 8,192
  float*          G      = (float*)(ws + 169877504);             // 524,288
  unsigned short* Abd    = (unsigned short*)(ws + 170401792);    // 1,048,576
  unsigned short* Mt     = (unsigned short*)(ws + 171450368);    // 1,048,576
  unsigned short* p1     = x_bf;  // x_bf dead after fused_qkv

  hipMemsetAsync(ss, 0, 8192, stream);
  hipMemsetAsync(Abd, 0, 1048576, stream);

  convert_x<<<16384, 256, 0, stream>>>(x, x_bf);
  prep_w<<<1024, 256, 0, stream>>>(Wq, Wk, Wv, Wp, Wcat_t, Wp_t);

  fused_qkv<<<dim3(8, 128, 2), 256, 0, stream>>>(x_bf, Wcat_t, v, Gp, ss);
  reduce_g<<<512, 256, 0, stream>>>(Gp, G);
  softmax_kernel<<<dim3(4, 2, 1), 256, 0, stream>>>(G, ss, rsc, Abd);

  // Mt[b] = Wp_t @ Abd[b]^T : M=512 N=512 K=512, batch 2
  gemm_lds<<<dim3(4, 4, 2), 256, 0, stream>>>(
      Wp_t, Abd, Mt, nullptr, 512, 512, 512, 512, 0L, 262144L, 262144L);

  // out_c[b] = v @ Mt[b]^T + bp : M=16384 N=512 K=512, batch 2
  gemm_lds<<<dim3(4, 128, 2), 256, 0, stream>>>(
      v, Mt, out_c, bp, 512, 512, 512, 512,
      (long)16384 * 512, 262144L, (long)16384 * 512);

  dwconv_kernel<true><<<dim3(16, 32, 2), 256, 0, stream>>>(
      v, pw1, nullptr, p1, nullptr);
  dwconv_kernel<false><<<dim3(16, 32, 2), 256, 0, stream>>>(
      p1, pw2, out_c, nullptr, out);
}